// Round 1
// baseline (238.918 us; speedup 1.0000x reference)
//
#include <hip/hip_runtime.h>

#define BATCH 4
#define CH    256
#define NPIX  4096
#define CQD   32

typedef __bf16 bf16;
typedef bf16 bf16x8 __attribute__((ext_vector_type(8)));
typedef bf16 bf16x4 __attribute__((ext_vector_type(4)));
typedef float f32x4 __attribute__((ext_vector_type(4)));

// ---------------------------------------------------------------------------
// Kernel 1: fused 1x1-conv projections via MFMA.
//   q' = (Wq x + bq)/64  -> qp [B][N][32] bf16   (pre-scaled by 1/sqrt(N))
//   k  = (Wk x + bk)     -> kp [B][N][32] bf16
//   vT = (Wv x + bv)     -> vT [B][C][N]  bf16   (transposed for PV B-operand)
// Block: 256 thr (4 waves), handles one (b, 64-pixel) tile, all 320 channels.
// ---------------------------------------------------------------------------
__global__ __launch_bounds__(256) void proj_kernel(
    const float* __restrict__ x,
    const float* __restrict__ Wq, const float* __restrict__ bq,
    const float* __restrict__ Wk, const float* __restrict__ bk,
    const float* __restrict__ Wv, const float* __restrict__ bv,
    bf16* __restrict__ qp, bf16* __restrict__ kp, bf16* __restrict__ vT)
{
    // xT[n_local][c], stride 264 elems = 528 B (16B-mult, bank-stride 4 -> 2-way max)
    __shared__ __align__(16) bf16 xT[64][264];

    const int t  = threadIdx.x;
    const int b  = blockIdx.x >> 6;
    const int n0 = (blockIdx.x & 63) << 6;

    const float* xb = x + (size_t)b * CH * NPIX;
    // stage x[b][0:256][n0:n0+64] -> xT (bf16, transposed). 4096 float4 chunks.
#pragma unroll
    for (int j = 0; j < 16; ++j) {
        int id = t + j * 256;
        int c  = id >> 4;
        int n4 = (id & 15) << 2;
        float4 vv = *(const float4*)(xb + (size_t)c * NPIX + n0 + n4);
        xT[n4 + 0][c] = (bf16)vv.x;
        xT[n4 + 1][c] = (bf16)vv.y;
        xT[n4 + 2][c] = (bf16)vv.z;
        xT[n4 + 3][c] = (bf16)vv.w;
    }
    __syncthreads();

    const int w    = t >> 6;
    const int l16  = t & 15;
    const int quad = (t & 63) >> 4;

    // 20 row-tiles of 16 output channels; wave w owns tiles [5w, 5w+5)
    for (int rt = 0; rt < 5; ++rt) {
        int ro = w * 80 + rt * 16;  // global output row tile base (0..319)
        const float* Wp; const float* bp; float scale; int rbase; int kind;
        if (ro < 32)       { Wp = Wq; bp = bq; scale = 0.015625f; rbase = ro;      kind = 0; }
        else if (ro < 64)  { Wp = Wk; bp = bk; scale = 1.0f;      rbase = ro - 32; kind = 1; }
        else               { Wp = Wv; bp = bv; scale = 1.0f;      rbase = ro - 64; kind = 2; }

        // A-frags: A[m=l16][k=quad*8+j], k-chunks of 32 over K=256
        bf16x8 afrag[8];
        const float* wrow = Wp + (size_t)(rbase + l16) * CH + quad * 8;
#pragma unroll
        for (int kc = 0; kc < 8; ++kc) {
            float4 wa = *(const float4*)(wrow + kc * 32);
            float4 wb = *(const float4*)(wrow + kc * 32 + 4);
            bf16x8 a;
            a[0] = (bf16)wa.x; a[1] = (bf16)wa.y; a[2] = (bf16)wa.z; a[3] = (bf16)wa.w;
            a[4] = (bf16)wb.x; a[5] = (bf16)wb.y; a[6] = (bf16)wb.z; a[7] = (bf16)wb.w;
            afrag[kc] = a;
        }
#pragma unroll
        for (int nt = 0; nt < 4; ++nt) {
            f32x4 acc = {0.f, 0.f, 0.f, 0.f};
#pragma unroll
            for (int kc = 0; kc < 8; ++kc) {
                bf16x8 bfr = *(const bf16x8*)&xT[nt * 16 + l16][kc * 32 + quad * 8];
                acc = __builtin_amdgcn_mfma_f32_16x16x32_bf16(afrag[kc], bfr, acc, 0, 0, 0);
            }
            // D[m=quad*4+r][n=nt*16+l16]
#pragma unroll
            for (int r = 0; r < 4; ++r) {
                int crow = rbase + quad * 4 + r;
                int n    = n0 + nt * 16 + l16;
                float val = (acc[r] + bp[crow]) * scale;
                if (kind == 0)      qp[((size_t)b * NPIX + n) * CQD + crow] = (bf16)val;
                else if (kind == 1) kp[((size_t)b * NPIX + n) * CQD + crow] = (bf16)val;
                else                vT[((size_t)b * CH + crow) * NPIX + n]  = (bf16)val;
            }
        }
    }
}

// ---------------------------------------------------------------------------
// Kernel 2: flash attention. Block = 256 thr (4 waves x 16 q-rows = 64 rows),
// grid = B * N/64 = 256. m-loop over 64-key tiles; online softmax; P via LDS
// round-trip (C-layout -> A-layout); O accum [16 rows][256 cols] per wave.
// q' already carries the 1/sqrt(N) scale.
// ---------------------------------------------------------------------------
__global__ __launch_bounds__(256) void attn_kernel(
    const bf16* __restrict__ qp, const bf16* __restrict__ kp,
    const bf16* __restrict__ vT, float* __restrict__ out)
{
    __shared__ __align__(16) bf16 Kt[64][40];      //  5 KB, 80B stride (16B-mult)
    __shared__ __align__(16) bf16 Vt[256][72];     // 36 KB, 144B stride
    __shared__ __align__(16) bf16 Pb[4][16][72];   //  9 KB

    const int t    = threadIdx.x;
    const int b    = blockIdx.x >> 6;
    const int n0   = (blockIdx.x & 63) << 6;
    const int w    = t >> 6;
    const int l16  = t & 15;
    const int quad = (t & 63) >> 4;

    // Q A-frag: A[m=l16][k=quad*8+j], one frag covers full CQ=32
    const bf16* qpb = qp + ((size_t)b * NPIX + n0 + w * 16) * CQD;
    bf16x8 qfrag = *(const bf16x8*)(qpb + (size_t)l16 * CQD + quad * 8);

    f32x4 o[16];
#pragma unroll
    for (int i = 0; i < 16; ++i) o[i] = (f32x4){0.f, 0.f, 0.f, 0.f};
    float mrow[4], lrow[4];
#pragma unroll
    for (int r = 0; r < 4; ++r) { mrow[r] = -1e30f; lrow[r] = 0.f; }

    const bf16* kpb = kp + (size_t)b * NPIX * CQD;
    const bf16* vTb = vT + (size_t)b * CH * NPIX;

    for (int mi = 0; mi < 64; ++mi) {
        const int m0 = mi << 6;
        // stage Kt[64][32] (kp rows m0..m0+63): 512 8B-chunks
#pragma unroll
        for (int j = 0; j < 2; ++j) {
            int id = t + j * 256;
            int row = id >> 3, c4 = (id & 7) * 4;
            *(bf16x4*)&Kt[row][c4] = *(const bf16x4*)(kpb + (size_t)(m0 + row) * CQD + c4);
        }
        // stage Vt[256][64] (vT cols m0..m0+63): 2048 16B-chunks
#pragma unroll
        for (int j = 0; j < 8; ++j) {
            int id = t + j * 256;
            int row = id >> 3, c8 = (id & 7) * 8;
            *(bf16x8*)&Vt[row][c8] = *(const bf16x8*)(vTb + (size_t)row * NPIX + m0 + c8);
        }
        __syncthreads();

        // S[16][64] = Q Kt^T : 4 MFMAs; B[k=q][n=m] from Kt[m][q]
        f32x4 s[4];
#pragma unroll
        for (int mt = 0; mt < 4; ++mt) {
            bf16x8 kfrag = *(const bf16x8*)&Kt[mt * 16 + l16][quad * 8];
            f32x4 z = {0.f, 0.f, 0.f, 0.f};
            s[mt] = __builtin_amdgcn_mfma_f32_16x16x32_bf16(qfrag, kfrag, z, 0, 0, 0);
        }

        // online softmax; row = quad*4+r is lane-local, cols spread over 16 lanes
        float p[4][4]; float alpha[4];
#pragma unroll
        for (int r = 0; r < 4; ++r) {
            float tm = fmaxf(fmaxf(s[0][r], s[1][r]), fmaxf(s[2][r], s[3][r]));
#pragma unroll
            for (int off = 8; off >= 1; off >>= 1) tm = fmaxf(tm, __shfl_xor(tm, off));
            float mn = fmaxf(mrow[r], tm);
            alpha[r] = __expf(mrow[r] - mn);
            float rs = 0.f;
#pragma unroll
            for (int mt = 0; mt < 4; ++mt) {
                float e = __expf(s[mt][r] - mn);
                p[mt][r] = e; rs += e;
            }
#pragma unroll
            for (int off = 8; off >= 1; off >>= 1) rs += __shfl_xor(rs, off);
            lrow[r] = lrow[r] * alpha[r] + rs;
            mrow[r] = mn;
        }
        // rescale O accumulators (rows lane-local -> pure VALU)
#pragma unroll
        for (int i = 0; i < 16; ++i)
#pragma unroll
            for (int r = 0; r < 4; ++r) o[i][r] *= alpha[r];

        // P: C-layout [row=quad*4+r][col=mt*16+l16] -> LDS
#pragma unroll
        for (int mt = 0; mt < 4; ++mt)
#pragma unroll
            for (int r = 0; r < 4; ++r)
                Pb[w][quad * 4 + r][mt * 16 + l16] = (bf16)p[mt][r];

        __syncthreads();  // P visible (and Vt staging already synced above)

        // O += P V : A[m=l16][k] from Pb, B[k=m][n=c] from Vt[c][m]
        bf16x8 pf0 = *(const bf16x8*)&Pb[w][l16][quad * 8];
        bf16x8 pf1 = *(const bf16x8*)&Pb[w][l16][32 + quad * 8];
#pragma unroll
        for (int ct = 0; ct < 16; ++ct) {
            bf16x8 v0 = *(const bf16x8*)&Vt[ct * 16 + l16][quad * 8];
            bf16x8 v1 = *(const bf16x8*)&Vt[ct * 16 + l16][32 + quad * 8];
            o[ct] = __builtin_amdgcn_mfma_f32_16x16x32_bf16(pf0, v0, o[ct], 0, 0, 0);
            o[ct] = __builtin_amdgcn_mfma_f32_16x16x32_bf16(pf1, v1, o[ct], 0, 0, 0);
        }
        __syncthreads();  // protect Kt/Vt before next staging
    }

    // epilogue: out[b][n][c] fp32, n = n0 + w*16 + quad*4 + r, c = ct*16 + l16
    float* ob = out + ((size_t)b * NPIX + n0 + w * 16) * CH;
#pragma unroll
    for (int ct = 0; ct < 16; ++ct)
#pragma unroll
        for (int r = 0; r < 4; ++r)
            ob[(size_t)(quad * 4 + r) * CH + ct * 16 + l16] = o[ct][r] / lrow[r];
}

extern "C" void kernel_launch(void* const* d_in, const int* in_sizes, int n_in,
                              void* d_out, int out_size, void* d_ws, size_t ws_size,
                              hipStream_t stream) {
    const float* x  = (const float*)d_in[0];
    const float* Wq = (const float*)d_in[1];
    const float* bq = (const float*)d_in[2];
    const float* Wk = (const float*)d_in[3];
    const float* bk = (const float*)d_in[4];
    const float* Wv = (const float*)d_in[5];
    const float* bv = (const float*)d_in[6];
    float* out = (float*)d_out;

    bf16* qp = (bf16*)d_ws;                              // [B][N][32]  1 MB
    bf16* kp = qp + (size_t)BATCH * NPIX * CQD;          // [B][N][32]  1 MB
    bf16* vT = kp + (size_t)BATCH * NPIX * CQD;          // [B][C][N]   8.4 MB

    proj_kernel<<<dim3(BATCH * (NPIX / 64)), dim3(256), 0, stream>>>(
        x, Wq, bq, Wk, bk, Wv, bv, qp, kp, vT);
    attn_kernel<<<dim3(BATCH * (NPIX / 64)), dim3(256), 0, stream>>>(
        qp, kp, vT, out);
}

// Round 3
// 157.866 us; speedup vs baseline: 1.5134x; 1.5134x over previous
//
#include <hip/hip_runtime.h>

#define BATCH 4
#define CH    256
#define NPIX  4096
#define CQD   32

typedef __bf16 bf16;
typedef bf16 bf16x8 __attribute__((ext_vector_type(8)));
typedef bf16 bf16x4 __attribute__((ext_vector_type(4)));
typedef float f32x4 __attribute__((ext_vector_type(4)));

#define MFMA16 __builtin_amdgcn_mfma_f32_16x16x32_bf16

// ---------------------------------------------------------------------------
// Kernel 1: fused 1x1-conv projections via MFMA.
//   q' = (Wq x + bq)/64 -> qp [B][N][32] bf16 ; k -> kp [B][N][32] bf16
//   vT = (Wv x + bv)    -> vT [B][C][N] bf16
// ---------------------------------------------------------------------------
__global__ __launch_bounds__(256) void proj_kernel(
    const float* __restrict__ x,
    const float* __restrict__ Wq, const float* __restrict__ bq,
    const float* __restrict__ Wk, const float* __restrict__ bk,
    const float* __restrict__ Wv, const float* __restrict__ bv,
    bf16* __restrict__ qp, bf16* __restrict__ kp, bf16* __restrict__ vT)
{
    __shared__ __align__(16) bf16 xT[64][264];       // [n_local][c]
    __shared__ __align__(16) bf16 vstage[4][16][72]; // per-wave transpose bounce

    const int t  = threadIdx.x;
    const int b  = blockIdx.x >> 6;
    const int n0 = (blockIdx.x & 63) << 6;

    const float* xb = x + (size_t)b * CH * NPIX;
#pragma unroll
    for (int j = 0; j < 16; ++j) {
        int id = t + j * 256;
        int c  = id >> 4;
        int n4 = (id & 15) << 2;
        float4 vv = *(const float4*)(xb + (size_t)c * NPIX + n0 + n4);
        xT[n4 + 0][c] = (bf16)vv.x;
        xT[n4 + 1][c] = (bf16)vv.y;
        xT[n4 + 2][c] = (bf16)vv.z;
        xT[n4 + 3][c] = (bf16)vv.w;
    }
    __syncthreads();

    const int w    = t >> 6;
    const int lane = t & 63;
    const int l16  = t & 15;
    const int quad = (t & 63) >> 4;

    for (int rt = 0; rt < 5; ++rt) {
        int ro = w * 80 + rt * 16;
        const float* Wp; const float* bp; float scale; int rbase; int kind;
        if (ro < 32)       { Wp = Wq; bp = bq; scale = 0.015625f; rbase = ro;      kind = 0; }
        else if (ro < 64)  { Wp = Wk; bp = bk; scale = 1.0f;      rbase = ro - 32; kind = 1; }
        else               { Wp = Wv; bp = bv; scale = 1.0f;      rbase = ro - 64; kind = 2; }

        bf16x8 afrag[8];
        const float* wrow = Wp + (size_t)(rbase + l16) * CH + quad * 8;
#pragma unroll
        for (int kc = 0; kc < 8; ++kc) {
            float4 wa = *(const float4*)(wrow + kc * 32);
            float4 wb = *(const float4*)(wrow + kc * 32 + 4);
            bf16x8 a;
            a[0] = (bf16)wa.x; a[1] = (bf16)wa.y; a[2] = (bf16)wa.z; a[3] = (bf16)wa.w;
            a[4] = (bf16)wb.x; a[5] = (bf16)wb.y; a[6] = (bf16)wb.z; a[7] = (bf16)wb.w;
            afrag[kc] = a;
        }
#pragma unroll
        for (int nt = 0; nt < 4; ++nt) {
            f32x4 acc = {0.f, 0.f, 0.f, 0.f};
#pragma unroll
            for (int kc = 0; kc < 8; ++kc) {
                bf16x8 bfr = *(const bf16x8*)&xT[nt * 16 + l16][kc * 32 + quad * 8];
                acc = MFMA16(afrag[kc], bfr, acc, 0, 0, 0);
            }
            if (kind != 2) {
                bf16x4 pk;
#pragma unroll
                for (int r = 0; r < 4; ++r)
                    pk[r] = (bf16)((acc[r] + bp[rbase + quad * 4 + r]) * scale);
                int n = n0 + nt * 16 + l16;
                bf16* dst = (kind == 0) ? qp : kp;
                *(bf16x4*)&dst[((size_t)b * NPIX + n) * CQD + rbase + quad * 4] = pk;
            } else {
#pragma unroll
                for (int r = 0; r < 4; ++r)
                    vstage[w][quad * 4 + r][nt * 16 + l16] =
                        (bf16)(acc[r] + bp[rbase + quad * 4 + r]);
            }
        }
        if (kind == 2) {
            // FIX(R3): 16 rows x 64 cols = 2048 bf16 needs TWO passes of
            // 64 lanes x 16B (was vcc=lane&3 covering only cols 0..31).
            int vrow = lane >> 3, vcc = lane & 7;
#pragma unroll
            for (int pass = 0; pass < 2; ++pass) {
                bf16x8 chunk = *(const bf16x8*)&vstage[w][pass * 8 + vrow][vcc * 8];
                *(bf16x8*)&vT[((size_t)b * CH + rbase + pass * 8 + vrow) * NPIX +
                              n0 + vcc * 8] = chunk;
            }
        }
    }
}

// ---------------------------------------------------------------------------
// Kernel 2: split-K flash attention. Block = 256 thr (4 waves), 128 q-rows
// (each wave 32 rows via 2 groups sharing every Vt read). Grid = 128*S.
// S^T orientation: softmax in-lane + xor16/32; Pb wave-private (no barrier);
// Vt XOR-swizzled unpadded. 2 barriers / key-iter.
// ---------------------------------------------------------------------------
template<int S, bool DIRECT>
__global__ __launch_bounds__(256, 2) void attn_kernel(
    const bf16* __restrict__ qp, const bf16* __restrict__ kp,
    const bf16* __restrict__ vT,
    bf16* __restrict__ Opart, float* __restrict__ Mpart, float* __restrict__ Lpart,
    float* __restrict__ out)
{
    __shared__ __align__(16) bf16 Kt[64][40];        // 5.0 KB (80B stride)
    __shared__ __align__(16) bf16 Vt[256][64];       // 32 KB, chunk' = chunk^(row&7)
    __shared__ __align__(16) bf16 Pb[4][2][16][72];  // 18 KB, wave-private

    const int t    = threadIdx.x;
    const int bid  = blockIdx.x;
    const int s    = bid % S;
    const int tq   = bid / S;
    const int b    = tq >> 5;
    const int qt   = tq & 31;
    const int n0   = qt << 7;
    const int w    = t >> 6;
    const int lane = t & 63;
    const int l16  = t & 15;
    const int quad = (t & 63) >> 4;

    const bf16* qpb = qp + ((size_t)b * NPIX + n0 + w * 32) * CQD;
    bf16x8 qfrag[2];
    qfrag[0] = *(const bf16x8*)(qpb + (size_t)l16 * CQD + quad * 8);
    qfrag[1] = *(const bf16x8*)(qpb + (size_t)(16 + l16) * CQD + quad * 8);

    f32x4 o[2][16];
#pragma unroll
    for (int g = 0; g < 2; ++g)
#pragma unroll
        for (int ct = 0; ct < 16; ++ct) o[g][ct] = (f32x4){0.f, 0.f, 0.f, 0.f};
    float m_g[2] = {-1e30f, -1e30f}, l_g[2] = {0.f, 0.f};

    const bf16* kpb = kp + (size_t)b * NPIX * CQD;
    const bf16* vTb = vT + (size_t)b * CH * NPIX;
    const int k0 = s * (NPIX / S);
    const int sw = l16 & 7;

    for (int mi = 0; mi < NPIX / S / 64; ++mi) {
        const int m0 = k0 + (mi << 6);
        {   // Kt: 64 rows x 32 cq = 256 x 16B chunks, 1/thread
            int row = t >> 2, cc = t & 3;
            *(bf16x8*)&Kt[row][cc * 8] =
                *(const bf16x8*)(kpb + (size_t)(m0 + row) * CQD + cc * 8);
        }
#pragma unroll
        for (int j = 0; j < 8; ++j) {  // Vt: 256 rows x 64 keys, swizzled
            int id  = t + j * 256;
            int row = id >> 3, cc = id & 7;
            *(bf16x8*)&Vt[row][(cc ^ (row & 7)) * 8] =
                *(const bf16x8*)(vTb + (size_t)row * NPIX + m0 + cc * 8);
        }
        __syncthreads();

        // S^T = K Q^T: D[row=key=quad*4+r][col=qrow=l16]
        f32x4 sv[2][4];
#pragma unroll
        for (int mt = 0; mt < 4; ++mt) {
            bf16x8 kfrag = *(const bf16x8*)&Kt[mt * 16 + l16][quad * 8];
            f32x4 z = {0.f, 0.f, 0.f, 0.f};
            sv[0][mt] = MFMA16(kfrag, qfrag[0], z, 0, 0, 0);
            sv[1][mt] = MFMA16(kfrag, qfrag[1], z, 0, 0, 0);
        }

#pragma unroll
        for (int g = 0; g < 2; ++g) {
            float tm = -1e30f;
#pragma unroll
            for (int mt = 0; mt < 4; ++mt)
#pragma unroll
                for (int r = 0; r < 4; ++r) tm = fmaxf(tm, sv[g][mt][r]);
            tm = fmaxf(tm, __shfl_xor(tm, 16));
            tm = fmaxf(tm, __shfl_xor(tm, 32));
            float mn    = fmaxf(m_g[g], tm);
            float alpha = __expf(m_g[g] - mn);
            float rs = 0.f;
#pragma unroll
            for (int mt = 0; mt < 4; ++mt) {
                bf16x4 pk;
#pragma unroll
                for (int r = 0; r < 4; ++r) {
                    float e = __expf(sv[g][mt][r] - mn);
                    rs += e;
                    pk[r] = (bf16)e;
                }
                *(bf16x4*)&Pb[w][g][l16][mt * 16 + quad * 4] = pk;
            }
            rs += __shfl_xor(rs, 16);
            rs += __shfl_xor(rs, 32);
            l_g[g] = l_g[g] * alpha + rs;
            m_g[g] = mn;
            float ar[4];
#pragma unroll
            for (int r = 0; r < 4; ++r) ar[r] = __shfl(alpha, quad * 4 + r);
#pragma unroll
            for (int ct = 0; ct < 16; ++ct)
#pragma unroll
                for (int r = 0; r < 4; ++r) o[g][ct][r] *= ar[r];
        }

        // PV: A = P-frag (wave-private Pb, no barrier), B = Vt (shared by both g)
        bf16x8 pf[2][2];
#pragma unroll
        for (int g = 0; g < 2; ++g)
#pragma unroll
            for (int kc = 0; kc < 2; ++kc)
                pf[g][kc] = *(const bf16x8*)&Pb[w][g][l16][kc * 32 + quad * 8];
#pragma unroll
        for (int ct = 0; ct < 16; ++ct) {
            int row = ct * 16 + l16;
            bf16x8 v0 = *(const bf16x8*)&Vt[row][((quad) ^ sw) * 8];
            bf16x8 v1 = *(const bf16x8*)&Vt[row][((4 + quad) ^ sw) * 8];
            o[0][ct] = MFMA16(pf[0][0], v0, o[0][ct], 0, 0, 0);
            o[0][ct] = MFMA16(pf[0][1], v1, o[0][ct], 0, 0, 0);
            o[1][ct] = MFMA16(pf[1][0], v0, o[1][ct], 0, 0, 0);
            o[1][ct] = MFMA16(pf[1][1], v1, o[1][ct], 0, 0, 0);
        }
        __syncthreads();  // protect Kt/Vt before next staging
    }

    if (!DIRECT) {
        const size_t prb = (((size_t)s * BATCH + b) * 32 + qt) * 128 + w * 32;
        if (quad == 0) {
#pragma unroll
            for (int g = 0; g < 2; ++g) {
                Mpart[prb + g * 16 + l16] = m_g[g];
                Lpart[prb + g * 16 + l16] = l_g[g];
            }
        }
#pragma unroll
        for (int g = 0; g < 2; ++g) {
            float rinv[4];
#pragma unroll
            for (int r = 0; r < 4; ++r) rinv[r] = 1.0f / __shfl(l_g[g], quad * 4 + r);
#pragma unroll
            for (int h = 0; h < 4; ++h) {
#pragma unroll
                for (int c2 = 0; c2 < 4; ++c2) {
                    int ct = h * 4 + c2;
#pragma unroll
                    for (int r = 0; r < 4; ++r)
                        Pb[w][0][quad * 4 + r][c2 * 16 + l16] = (bf16)(o[g][ct][r] * rinv[r]);
                }
                // FIX(R3): 16 rows x 64 cols needs TWO 64-lane x 16B passes
                // (was vcc=lane&3 covering only cols 0..31 -> half of Opart
                // left poisoned).
                int vrow = lane >> 3, vcc = lane & 7;
#pragma unroll
                for (int pass = 0; pass < 2; ++pass) {
                    bf16x8 chunk = *(const bf16x8*)&Pb[w][0][pass * 8 + vrow][vcc * 8];
                    *(bf16x8*)&Opart[(prb + g * 16 + pass * 8 + vrow) * CH +
                                     h * 64 + vcc * 8] = chunk;
                }
            }
        }
    } else {
        float* ob = out + ((size_t)b * NPIX + n0 + w * 32) * CH;
#pragma unroll
        for (int g = 0; g < 2; ++g) {
            float rinv[4];
#pragma unroll
            for (int r = 0; r < 4; ++r) rinv[r] = 1.0f / __shfl(l_g[g], quad * 4 + r);
#pragma unroll
            for (int ct = 0; ct < 16; ++ct)
#pragma unroll
                for (int r = 0; r < 4; ++r)
                    ob[(size_t)(g * 16 + quad * 4 + r) * CH + ct * 16 + l16] =
                        o[g][ct][r] * rinv[r];
        }
    }
}

// ---------------------------------------------------------------------------
// Kernel 3: merge S split-K partials. 1 thread = 8 channels of one (b,n) row.
// ---------------------------------------------------------------------------
template<int S>
__global__ __launch_bounds__(256) void combine_kernel(
    const bf16* __restrict__ Opart, const float* __restrict__ Mpart,
    const float* __restrict__ Lpart, float* __restrict__ out)
{
    int idx  = blockIdx.x * 256 + threadIdx.x;       // B*N*(C/8) = 524288
    int nrow = idx >> 5;
    int cc   = (idx & 31) * 8;
    int b    = nrow >> 12, nin = nrow & 4095;
    int qt   = nin >> 7,  rl  = nin & 127;

    size_t pr[S];
    float  mmax = -1e30f;
    float  ms[S], ls[S];
#pragma unroll
    for (int s = 0; s < S; ++s) {
        pr[s] = (((size_t)s * BATCH + b) * 32 + qt) * 128 + rl;
        ms[s] = Mpart[pr[s]];
        ls[s] = Lpart[pr[s]];
        mmax  = fmaxf(mmax, ms[s]);
    }
    float wsum = 0.f, wgt[S];
#pragma unroll
    for (int s = 0; s < S; ++s) { wgt[s] = ls[s] * __expf(ms[s] - mmax); wsum += wgt[s]; }
    float inv = 1.0f / wsum;

    float acc[8] = {0.f, 0.f, 0.f, 0.f, 0.f, 0.f, 0.f, 0.f};
#pragma unroll
    for (int s = 0; s < S; ++s) {
        bf16x8 ov = *(const bf16x8*)&Opart[pr[s] * CH + cc];
        float wn = wgt[s] * inv;
#pragma unroll
        for (int j = 0; j < 8; ++j) acc[j] += wn * (float)ov[j];
    }
    float4 o0 = {acc[0], acc[1], acc[2], acc[3]};
    float4 o1 = {acc[4], acc[5], acc[6], acc[7]};
    *(float4*)&out[(size_t)nrow * CH + cc]     = o0;
    *(float4*)&out[(size_t)nrow * CH + cc + 4] = o1;
}

extern "C" void kernel_launch(void* const* d_in, const int* in_sizes, int n_in,
                              void* d_out, int out_size, void* d_ws, size_t ws_size,
                              hipStream_t stream) {
    const float* x  = (const float*)d_in[0];
    const float* Wq = (const float*)d_in[1];
    const float* bq = (const float*)d_in[2];
    const float* Wk = (const float*)d_in[3];
    const float* bk = (const float*)d_in[4];
    const float* Wv = (const float*)d_in[5];
    const float* bv = (const float*)d_in[6];
    float* out = (float*)d_out;

    char* ws = (char*)d_ws;
    const size_t qpB   = (size_t)BATCH * NPIX * CQD * 2;   // 1 MB
    const size_t vTB   = (size_t)BATCH * CH * NPIX * 2;    // 8 MB
    const size_t baseB = 2 * qpB + vTB;                    // 10.5 MB
    const size_t oprtB = (size_t)BATCH * NPIX * CH * 2;    // 8.4 MB per split
    const size_t mlB   = (size_t)BATCH * NPIX * 4;         // 64 KB per split

    bf16* qp = (bf16*)ws;
    bf16* kp = (bf16*)(ws + qpB);
    bf16* vT = (bf16*)(ws + 2 * qpB);

    proj_kernel<<<dim3(BATCH * (NPIX / 64)), dim3(256), 0, stream>>>(
        x, Wq, bq, Wk, bk, Wv, bv, qp, kp, vT);

    auto need = [&](int S) { return baseB + (size_t)S * (oprtB + 2 * mlB); };
    int S = (ws_size >= need(4)) ? 4 : (ws_size >= need(2)) ? 2
          : (ws_size >= need(1)) ? 1 : 0;

    if (S > 0) {
        bf16*  Opart = (bf16*)(ws + baseB);
        float* Mpart = (float*)(ws + baseB + (size_t)S * oprtB);
        float* Lpart = (float*)(ws + baseB + (size_t)S * oprtB + (size_t)S * mlB);
        if (S == 4) {
            attn_kernel<4, false><<<dim3(128 * 4), dim3(256), 0, stream>>>(
                qp, kp, vT, Opart, Mpart, Lpart, out);
            combine_kernel<4><<<dim3(2048), dim3(256), 0, stream>>>(Opart, Mpart, Lpart, out);
        } else if (S == 2) {
            attn_kernel<2, false><<<dim3(128 * 2), dim3(256), 0, stream>>>(
                qp, kp, vT, Opart, Mpart, Lpart, out);
            combine_kernel<2><<<dim3(2048), dim3(256), 0, stream>>>(Opart, Mpart, Lpart, out);
        } else {
            attn_kernel<1, false><<<dim3(128), dim3(256), 0, stream>>>(
                qp, kp, vT, Opart, Mpart, Lpart, out);
            combine_kernel<1><<<dim3(2048), dim3(256), 0, stream>>>(Opart, Mpart, Lpart, out);
        }
    } else {
        attn_kernel<1, true><<<dim3(128), dim3(256), 0, stream>>>(
            qp, kp, vT, nullptr, nullptr, nullptr, out);
    }
}